// Round 4
// baseline (1342.039 us; speedup 1.0000x reference)
//
#include <hip/hip_runtime.h>
#include <hip/hip_bf16.h>
#include <math.h>
#include <stdint.h>

typedef short short8 __attribute__((ext_vector_type(8)));
typedef float f32x4 __attribute__((ext_vector_type(4)));

__device__ __forceinline__ float bf2f(unsigned int u) {
    union { unsigned int i; float f; } x; x.i = u << 16; return x.f;
}
__device__ __forceinline__ unsigned short f2bf(float f) {
    union { float f; unsigned int i; } x; x.f = f;
    unsigned int r = x.i + 0x7fffu + ((x.i >> 16) & 1u);
    return (unsigned short)(r >> 16);
}

// ---------------- CSR build ----------------
__global__ void zero_i(int* __restrict__ p, int n) {
    int i = blockIdx.x * blockDim.x + threadIdx.x;
    if (i < n) p[i] = 0;
}
__global__ void hist_k(const int* __restrict__ row, int* __restrict__ deg, int E) {
    int e = blockIdx.x * blockDim.x + threadIdx.x;
    if (e < E) atomicAdd(&deg[row[e]], 1);
}
__global__ void block_sums(const int* __restrict__ deg, int* __restrict__ bs, int N) {
    __shared__ int tmp[256];
    int t = threadIdx.x;
    int i = blockIdx.x * 256 + t;
    tmp[t] = (i < N) ? deg[i] : 0;
    __syncthreads();
    for (int off = 128; off > 0; off >>= 1) {
        if (t < off) tmp[t] += tmp[t + off];
        __syncthreads();
    }
    if (t == 0) bs[blockIdx.x] = tmp[0];
}
__global__ void scan_bs(const int* __restrict__ bs, int* __restrict__ bo, int B) {
    __shared__ int tmp[256];
    int t = threadIdx.x;
    int v = (t < B) ? bs[t] : 0;
    tmp[t] = v;
    __syncthreads();
    for (int off = 1; off < 256; off <<= 1) {
        int x = (t >= off) ? tmp[t - off] : 0;
        __syncthreads();
        tmp[t] += x;
        __syncthreads();
    }
    bo[t] = tmp[t] - v;
}
__global__ void finalize_rowptr(const int* __restrict__ deg, const int* __restrict__ bo,
                                int* __restrict__ rowptr, int* __restrict__ cursor,
                                int N, int E) {
    __shared__ int tmp[256];
    int t = threadIdx.x;
    int i = blockIdx.x * 256 + t;
    int v = (i < N) ? deg[i] : 0;
    tmp[t] = v;
    __syncthreads();
    for (int off = 1; off < 256; off <<= 1) {
        int x = (t >= off) ? tmp[t - off] : 0;
        __syncthreads();
        tmp[t] += x;
        __syncthreads();
    }
    int excl = tmp[t] - v + bo[blockIdx.x];
    if (i < N) { rowptr[i] = excl; cursor[i] = excl; }
    if (i == N) rowptr[N] = E;
}
__global__ void fill_csr(const int* __restrict__ row, const int* __restrict__ col,
                         int* __restrict__ cursor, int* __restrict__ idx, int E) {
    int e = blockIdx.x * blockDim.x + threadIdx.x;
    if (e < E) {
        int p = atomicAdd(&cursor[row[e]], 1);
        idx[p] = col[e];
    }
}

// ---------------- misc prep ----------------
__global__ void zero3(uint4* a, int na, uint4* b, int nb, uint4* c, int nc) {
    int i = blockIdx.x * blockDim.x + threadIdx.x;
    uint4 z = make_uint4(0, 0, 0, 0);
    if (i < na) a[i] = z;
    if (i < nb) b[i] = z;
    if (i < nc) c[i] = z;
}

__global__ void conv_x(const float* __restrict__ x, unsigned short* __restrict__ xb, int total4) {
    int i = blockIdx.x * blockDim.x + threadIdx.x;
    if (i >= total4) return;
    float4 v = *(const float4*)(x + (size_t)i * 4);
    unsigned int lo = (unsigned int)f2bf(v.x) | ((unsigned int)f2bf(v.y) << 16);
    unsigned int hi = (unsigned int)f2bf(v.z) | ((unsigned int)f2bf(v.w) << 16);
    *(uint2*)(xb + (size_t)i * 4) = make_uint2(lo, hi);
}

// transpose+convert all 6 weight matrices into wt (bf16, [cols][K] layout)
__global__ void prep_weights(const float* __restrict__ W1_0, const float* __restrict__ W1rest,
                             const float* __restrict__ W2, unsigned short* __restrict__ wt) {
    int id = blockIdx.x * blockDim.x + threadIdx.x;
    if (id < 32768) {                       // W1_0 [128][256] -> [256][128]
        int k = id >> 8, c = id & 255;
        wt[c * 128 + k] = f2bf(W1_0[id]);
    } else if (id < 163840) {               // W1rest 2x [256][256]
        int t = id - 32768;
        int m = t >> 16, r = t & 65535;
        int k = r >> 8, c = r & 255;
        wt[32768 + m * 65536 + c * 256 + k] = f2bf(W1rest[t]);
    } else if (id < 360448) {               // W2 3x [256][256]
        int t = id - 163840;
        int m = t >> 16, r = t & 65535;
        int k = r >> 8, c = r & 255;
        wt[163840 + m * 65536 + c * 256 + k] = f2bf(W2[t]);
    }
}

// ---------------- chunked pull aggregation, optional fused BN+ReLU on source ----
// out[v] = (1+eps)*T(h[v]) + sum_{u in N(v)} T(h[u]),  T = identity or relu(bn(.))
// Column chunk of 32 (64B gathers); chunk = blockIdx.x % NCH so consecutive blocks
// (round-robin over the 8 XCDs) pin each column slice to one XCD's L2.
template<int H, bool FUSE_BN>
__global__ __launch_bounds__(256) void aggregate_c(
    const unsigned short* __restrict__ hsrc,
    const int* __restrict__ rowptr, const int* __restrict__ idx,
    const float* __restrict__ eps_p, int layer,
    const float* __restrict__ stats, const float* __restrict__ g,
    const float* __restrict__ bt, float invN,
    unsigned short* __restrict__ out, int N, int npw) {
    constexpr int NCH = H / 32;
    const int chunk = blockIdx.x % NCH;
    const int blk   = blockIdx.x / NCH;
    const int lane = threadIdx.x & 63;
    const int wave = threadIdx.x >> 6;
    const int sub = lane >> 4;
    const int cp  = lane & 15;
    const int colu = chunk * 16 + cp;   // uint (bf16-pair) index within row
    const int col = colu * 2;
    constexpr int HU = H / 2;

    float sc0 = 1.f, sh0 = 0.f, sc1 = 1.f, sh1 = 0.f;
    if constexpr (FUSE_BN) {
        float m0 = stats[col] * invN;
        float m1 = stats[col + 1] * invN;
        float q0 = stats[256 + col] * invN - m0 * m0;
        float q1 = stats[256 + col + 1] * invN - m1 * m1;
        sc0 = g[col] * rsqrtf(q0 + 1e-5f);
        sh0 = bt[col] - m0 * sc0;
        sc1 = g[col + 1] * rsqrtf(q1 + 1e-5f);
        sh1 = bt[col + 1] - m1 * sc1;
    }
    const float s = 1.f + eps_p[layer];
    const unsigned int* hu = (const unsigned int*)hsrc;

    const int v0 = (blk * 4 + wave) * npw;
    for (int vi = 0; vi < npw; ++vi) {
        int v = v0 + vi;
        if (v >= N) return;  // wave-uniform
        float a0 = 0.f, a1 = 0.f;
        if (sub == 0) {
            unsigned int r = hu[(size_t)v * HU + colu];
            float f0 = bf2f(r & 0xffffu), f1 = bf2f(r >> 16);
            if constexpr (FUSE_BN) {
                f0 = fmaxf(f0 * sc0 + sh0, 0.f);
                f1 = fmaxf(f1 * sc1 + sh1, 0.f);
            }
            a0 = s * f0; a1 = s * f1;
        }
        int e = rowptr[v] + sub, re = rowptr[v + 1];
        for (; e < re; e += 4) {
            int u = idx[e];
            unsigned int r = hu[(size_t)u * HU + colu];
            float f0 = bf2f(r & 0xffffu), f1 = bf2f(r >> 16);
            if constexpr (FUSE_BN) {
                f0 = fmaxf(f0 * sc0 + sh0, 0.f);
                f1 = fmaxf(f1 * sc1 + sh1, 0.f);
            }
            a0 += f0; a1 += f1;
        }
        a0 += __shfl_xor(a0, 16, 64); a0 += __shfl_xor(a0, 32, 64);
        a1 += __shfl_xor(a1, 16, 64); a1 += __shfl_xor(a1, 32, 64);
        if (sub == 0)
            ((unsigned int*)out)[(size_t)v * HU + colu] =
                (unsigned int)f2bf(a0) | ((unsigned int)f2bf(a1) << 16);
    }
}

// ---------------- bf16 MFMA GEMM + bias + BN column stats ----------------
// C^T trick: mfma(b, a) so each lane holds 4 CONSECUTIVE output cols for one row
// -> uint2 (8B) stores; stats via 16-lane butterfly.
template<int K>
__global__ __launch_bounds__(256) void gemm_mfma(const unsigned short* __restrict__ A,
                                                 const unsigned short* __restrict__ Wt,
                                                 const float* __restrict__ bias,
                                                 unsigned short* __restrict__ Y,
                                                 float* __restrict__ stats,
                                                 int Nrows) {
    __shared__ unsigned short sA[2][128 * 32];
    __shared__ unsigned short sB[2][128 * 32];
    const int tid = threadIdx.x;
    const int lane = tid & 63;
    const int wid = tid >> 6;
    const int wm = wid >> 1, wn = wid & 1;
    const int r0 = blockIdx.x * 128;
    const int c0 = blockIdx.y * 128;
    const int chunk0 = wid * 2;

    f32x4 acc[4][4] = {};  // [i(row-block)][n(col-block)], C^T fragments

    auto stage = [&](int buf, int k0) {
#pragma unroll
        for (int q = 0; q < 2; ++q) {
            int chunk = chunk0 + q;
            int byteoff = chunk * 1024 + lane * 16;
            int row = byteoff >> 6;
            int kk = (byteoff & 63) >> 1;
            const unsigned short* gA = A + (size_t)(r0 + row) * K + k0 + kk;
            const unsigned short* gB = Wt + (size_t)(c0 + row) * K + k0 + kk;
            __builtin_amdgcn_global_load_lds(
                (const __attribute__((address_space(1))) void*)(uintptr_t)gA,
                (__attribute__((address_space(3))) void*)(uintptr_t)(&sA[buf][chunk * 512]),
                16, 0, 0);
            __builtin_amdgcn_global_load_lds(
                (const __attribute__((address_space(1))) void*)(uintptr_t)gB,
                (__attribute__((address_space(3))) void*)(uintptr_t)(&sB[buf][chunk * 512]),
                16, 0, 0);
        }
    };

    const int nt = K / 32;
    stage(0, 0);
    const int krow = lane >> 4;
    const int rl = lane & 15;

    for (int t = 0; t < nt; ++t) {
        __syncthreads();
        if (t + 1 < nt) stage((t + 1) & 1, (t + 1) * 32);
        const unsigned short* sAb = sA[t & 1];
        const unsigned short* sBb = sB[t & 1];
        short8 a[4], b[4];
#pragma unroll
        for (int i = 0; i < 4; ++i) {
            a[i] = *(const short8*)(sAb + (wm * 64 + i * 16 + rl) * 32 + krow * 8);
            b[i] = *(const short8*)(sBb + (wn * 64 + i * 16 + rl) * 32 + krow * 8);
        }
#pragma unroll
        for (int i = 0; i < 4; ++i)
#pragma unroll
            for (int n = 0; n < 4; ++n)
                asm volatile("v_mfma_f32_16x16x32_bf16 %0, %1, %2, %0"
                             : "+v"(acc[i][n])
                             : "v"(b[n]), "v"(a[i]));   // swapped: result is C^T
    }
    asm volatile("s_nop 7\n\ts_nop 7" ::);

    // epilogue: lane holds C[row = r0+wm*64+i*16+(lane&15)][cb..cb+3],
    // cb = c0+wn*64+n*16+(lane>>4)*4
    const int ml = lane & 15, gl = lane >> 4;
    float4 bv[4];
#pragma unroll
    for (int n = 0; n < 4; ++n)
        bv[n] = *(const float4*)&bias[c0 + wn * 64 + n * 16 + gl * 4];

    float sacc[4][4] = {};  // [n][r]
    float qacc[4][4] = {};
#pragma unroll
    for (int i = 0; i < 4; ++i) {
        int row = r0 + wm * 64 + i * 16 + ml;
        bool ok = row < Nrows;
#pragma unroll
        for (int n = 0; n < 4; ++n) {
            float v0 = acc[i][n][0] + bv[n].x;
            float v1 = acc[i][n][1] + bv[n].y;
            float v2 = acc[i][n][2] + bv[n].z;
            float v3 = acc[i][n][3] + bv[n].w;
            uint2 w;
            w.x = (unsigned int)f2bf(v0) | ((unsigned int)f2bf(v1) << 16);
            w.y = (unsigned int)f2bf(v2) | ((unsigned int)f2bf(v3) << 16);
            *(uint2*)&Y[(size_t)row * 256 + c0 + wn * 64 + n * 16 + gl * 4] = w;
            if (ok) {
                sacc[n][0] += v0; sacc[n][1] += v1; sacc[n][2] += v2; sacc[n][3] += v3;
                qacc[n][0] += v0 * v0; qacc[n][1] += v1 * v1;
                qacc[n][2] += v2 * v2; qacc[n][3] += v3 * v3;
            }
        }
    }
    // reduce over the 16 rows held by lanes sharing gl (consecutive 16 lanes)
#pragma unroll
    for (int n = 0; n < 4; ++n)
#pragma unroll
        for (int r = 0; r < 4; ++r) {
            float s = sacc[n][r], q = qacc[n][r];
            s += __shfl_xor(s, 1, 64); q += __shfl_xor(q, 1, 64);
            s += __shfl_xor(s, 2, 64); q += __shfl_xor(q, 2, 64);
            s += __shfl_xor(s, 4, 64); q += __shfl_xor(q, 4, 64);
            s += __shfl_xor(s, 8, 64); q += __shfl_xor(q, 8, 64);
            sacc[n][r] = s; qacc[n][r] = q;
        }
    if (ml == 0) {
#pragma unroll
        for (int n = 0; n < 4; ++n)
#pragma unroll
            for (int r = 0; r < 4; ++r) {
                int c = c0 + wn * 64 + n * 16 + gl * 4 + r;
                atomicAdd(&stats[c], sacc[n][r]);
                atomicAdd(&stats[256 + c], qacc[n][r]);
            }
    }
}

// ---------------- fused BN params + apply (+optional ReLU) ----------------
__global__ void bn_fuse(const unsigned short* __restrict__ Y, const float* __restrict__ stats,
                        const float* __restrict__ g, const float* __restrict__ bt,
                        float invN, unsigned short* __restrict__ outb, float* __restrict__ outf,
                        int total8, int relu) {
    int i = blockIdx.x * blockDim.x + threadIdx.x;
    if (i >= total8) return;
    int col0 = (i & 31) << 3;
    uint4 y = ((const uint4*)Y)[i];
    unsigned int yy[4] = {y.x, y.y, y.z, y.w};
    float o[8];
#pragma unroll
    for (int j = 0; j < 4; ++j) {
        o[2 * j]     = bf2f(yy[j] & 0xffffu);
        o[2 * j + 1] = bf2f(yy[j] >> 16);
    }
#pragma unroll
    for (int j = 0; j < 8; ++j) {
        int c = col0 + j;
        float mean = stats[c] * invN;
        float var = stats[256 + c] * invN - mean * mean;
        float sc = g[c] * rsqrtf(var + 1e-5f);
        float sh = bt[c] - mean * sc;
        float v = o[j] * sc + sh;
        if (relu) v = fmaxf(v, 0.f);
        o[j] = v;
    }
    if (outf) {
        float4* of = (float4*)outf;
        of[2 * i]     = make_float4(o[0], o[1], o[2], o[3]);
        of[2 * i + 1] = make_float4(o[4], o[5], o[6], o[7]);
    } else {
        uint4 w;
        w.x = (unsigned int)f2bf(o[0]) | ((unsigned int)f2bf(o[1]) << 16);
        w.y = (unsigned int)f2bf(o[2]) | ((unsigned int)f2bf(o[3]) << 16);
        w.z = (unsigned int)f2bf(o[4]) | ((unsigned int)f2bf(o[5]) << 16);
        w.w = (unsigned int)f2bf(o[6]) | ((unsigned int)f2bf(o[7]) << 16);
        ((uint4*)outb)[i] = w;
    }
}

extern "C" void kernel_launch(void* const* d_in, const int* in_sizes, int n_in,
                              void* d_out, int out_size, void* d_ws, size_t ws_size,
                              hipStream_t stream) {
    const float* x      = (const float*)d_in[0];
    const int*   ei     = (const int*)d_in[1];
    const float* eps    = (const float*)d_in[2];
    const float* W1_0   = (const float*)d_in[3];
    const float* W1rest = (const float*)d_in[4];
    const float* b1     = (const float*)d_in[5];
    const float* g1     = (const float*)d_in[6];
    const float* bt1    = (const float*)d_in[7];
    const float* W2     = (const float*)d_in[8];
    const float* b2     = (const float*)d_in[9];
    const float* g2     = (const float*)d_in[10];
    const float* bt2    = (const float*)d_in[11];

    const int N = in_sizes[0] / 128;
    const int E = in_sizes[1] / 2;
    const int* row = ei;
    const int* col = ei + E;
    const int Npad = ((N + 127) / 128) * 128;
    const int nbRow = Npad / 128;

    char* w = (char*)d_ws;
    auto alloc = [&](size_t bytes) {
        char* p = w;
        w += (bytes + 255) & ~(size_t)255;
        return p;
    };
    unsigned short* xb = (unsigned short*)alloc((size_t)Npad * 128 * 2);
    unsigned short* p0 = (unsigned short*)alloc((size_t)Npad * 256 * 2);
    unsigned short* Yb = (unsigned short*)alloc((size_t)Npad * 256 * 2);
    unsigned short* wt = (unsigned short*)alloc((size_t)360448 * 2);
    float* stats = (float*)alloc(3072 * 4);
    int* deg    = (int*)alloc((size_t)N * 4);
    int* cursor = (int*)alloc((size_t)N * 4);
    int* rowptr = (int*)alloc((size_t)(N + 1) * 4);
    int* bs     = (int*)alloc(256 * 4);
    int* bo     = (int*)alloc(256 * 4);
    int* idxb   = (int*)alloc((size_t)E * 4);

    const float invN = 1.f / (float)N;
    const int B = (N + 255) / 256;

    // CSR build
    zero_i<<<(N + 255) / 256, 256, 0, stream>>>(deg, N);
    hist_k<<<(E + 255) / 256, 256, 0, stream>>>(row, deg, E);
    block_sums<<<B, 256, 0, stream>>>(deg, bs, N);
    scan_bs<<<1, 256, 0, stream>>>(bs, bo, B);
    finalize_rowptr<<<B, 256, 0, stream>>>(deg, bo, rowptr, cursor, N, E);
    fill_csr<<<(E + 255) / 256, 256, 0, stream>>>(row, col, cursor, idxb, E);

    // zero: p0 tail, stats (every call, in-stream for graph replay)
    int tail16 = (Npad - N) * 256 * 2 / 16;
    {
        uint4* t0 = (uint4*)(p0 + (size_t)N * 256);
        int mx = tail16 > 768 ? tail16 : 768;
        zero3<<<(mx + 255) / 256, 256, 0, stream>>>(t0, tail16, t0, tail16, (uint4*)stats, 768);
    }

    conv_x<<<(N * 32 + 255) / 256, 256, 0, stream>>>(x, xb, N * 32);
    prep_weights<<<(360448 + 255) / 256, 256, 0, stream>>>(W1_0, W1rest, W2, wt);

    const int npw = 8;
    const int bpc = (N + 4 * npw - 1) / (4 * npw);  // blocks per chunk
    const int bnGrid = (N * 32 + 255) / 256;
    dim3 gg(nbRow, 2);

    for (int layer = 0; layer < 3; ++layer) {
        float* st = stats + layer * 1024;

        // aggregation -> p0 (layers 1,2: fused BN2(prev)+ReLU on the pre-BN Yb)
        if (layer == 0)
            aggregate_c<128, false><<<4 * bpc, 256, 0, stream>>>(
                xb, rowptr, idxb, eps, 0, nullptr, nullptr, nullptr, invN, p0, N, npw);
        else
            aggregate_c<256, true><<<8 * bpc, 256, 0, stream>>>(
                Yb, rowptr, idxb, eps, layer, stats + (layer - 1) * 1024 + 512,
                g2 + (layer - 1) * 256, bt2 + (layer - 1) * 256, invN, p0, N, npw);

        // Linear1 + stats
        if (layer == 0)
            gemm_mfma<128><<<gg, 256, 0, stream>>>(p0, wt, b1, Yb, st, N);
        else
            gemm_mfma<256><<<gg, 256, 0, stream>>>(p0, wt + 32768 + (size_t)(layer - 1) * 65536,
                                                   b1 + layer * 256, Yb, st, N);
        // BN1 + ReLU -> p0 (bf16)
        bn_fuse<<<bnGrid, 256, 0, stream>>>(Yb, st, g1 + layer * 256, bt1 + layer * 256,
                                            invN, p0, nullptr, N * 32, 1);
        // Linear2 + stats
        gemm_mfma<256><<<gg, 256, 0, stream>>>(p0, wt + 163840 + (size_t)layer * 65536,
                                               b2 + layer * 256, Yb, st + 512, N);
        // layers 0,1: BN2+ReLU applied inside next layer's aggregation.
        // final layer: BN2 -> fp32 d_out
        if (layer == 2)
            bn_fuse<<<bnGrid, 256, 0, stream>>>(Yb, st + 512, g2 + layer * 256, bt2 + layer * 256,
                                                invN, nullptr, (float*)d_out, N * 32, 0);
    }
}

// Round 5
// 554.453 us; speedup vs baseline: 2.4205x; 2.4205x over previous
//
#include <hip/hip_runtime.h>
#include <hip/hip_bf16.h>
#include <math.h>
#include <stdint.h>

typedef short short8 __attribute__((ext_vector_type(8)));
typedef float f32x4 __attribute__((ext_vector_type(4)));

__device__ __forceinline__ float bf2f(unsigned int u) {
    union { unsigned int i; float f; } x; x.i = u << 16; return x.f;
}
__device__ __forceinline__ unsigned short f2bf(float f) {
    union { float f; unsigned int i; } x; x.f = f;
    unsigned int r = x.i + 0x7fffu + ((x.i >> 16) & 1u);
    return (unsigned short)(r >> 16);
}

// ---------------- CSR build ----------------
__global__ void zero_i(int* __restrict__ p, int n) {
    int i = blockIdx.x * blockDim.x + threadIdx.x;
    if (i < n) p[i] = 0;
}
__global__ void hist_k(const int* __restrict__ row, int* __restrict__ deg, int E) {
    int e = blockIdx.x * blockDim.x + threadIdx.x;
    if (e < E) atomicAdd(&deg[row[e]], 1);
}
__global__ void block_sums(const int* __restrict__ deg, int* __restrict__ bs, int N) {
    __shared__ int tmp[256];
    int t = threadIdx.x;
    int i = blockIdx.x * 256 + t;
    tmp[t] = (i < N) ? deg[i] : 0;
    __syncthreads();
    for (int off = 128; off > 0; off >>= 1) {
        if (t < off) tmp[t] += tmp[t + off];
        __syncthreads();
    }
    if (t == 0) bs[blockIdx.x] = tmp[0];
}
__global__ void scan_bs(const int* __restrict__ bs, int* __restrict__ bo, int B) {
    __shared__ int tmp[256];
    int t = threadIdx.x;
    int v = (t < B) ? bs[t] : 0;
    tmp[t] = v;
    __syncthreads();
    for (int off = 1; off < 256; off <<= 1) {
        int x = (t >= off) ? tmp[t - off] : 0;
        __syncthreads();
        tmp[t] += x;
        __syncthreads();
    }
    bo[t] = tmp[t] - v;
}
__global__ void finalize_rowptr(const int* __restrict__ deg, const int* __restrict__ bo,
                                int* __restrict__ rowptr, int* __restrict__ cursor,
                                int N, int E) {
    __shared__ int tmp[256];
    int t = threadIdx.x;
    int i = blockIdx.x * 256 + t;
    int v = (i < N) ? deg[i] : 0;
    tmp[t] = v;
    __syncthreads();
    for (int off = 1; off < 256; off <<= 1) {
        int x = (t >= off) ? tmp[t - off] : 0;
        __syncthreads();
        tmp[t] += x;
        __syncthreads();
    }
    int excl = tmp[t] - v + bo[blockIdx.x];
    if (i < N) { rowptr[i] = excl; cursor[i] = excl; }
    if (i == N) rowptr[N] = E;
}
__global__ void fill_csr(const int* __restrict__ row, const int* __restrict__ col,
                         int* __restrict__ cursor, int* __restrict__ idx, int E) {
    int e = blockIdx.x * blockDim.x + threadIdx.x;
    if (e < E) {
        int p = atomicAdd(&cursor[row[e]], 1);
        idx[p] = col[e];
    }
}

// ---------------- misc prep ----------------
__global__ void zero3(uint4* a, int na, uint4* b, int nb, uint4* c, int nc) {
    int i = blockIdx.x * blockDim.x + threadIdx.x;
    uint4 z = make_uint4(0, 0, 0, 0);
    if (i < na) a[i] = z;
    if (i < nb) b[i] = z;
    if (i < nc) c[i] = z;
}

__global__ void conv_x(const float* __restrict__ x, unsigned short* __restrict__ xb, int total4) {
    int i = blockIdx.x * blockDim.x + threadIdx.x;
    if (i >= total4) return;
    float4 v = *(const float4*)(x + (size_t)i * 4);
    unsigned int lo = (unsigned int)f2bf(v.x) | ((unsigned int)f2bf(v.y) << 16);
    unsigned int hi = (unsigned int)f2bf(v.z) | ((unsigned int)f2bf(v.w) << 16);
    *(uint2*)(xb + (size_t)i * 4) = make_uint2(lo, hi);
}

// transpose+convert all 6 weight matrices into wt (bf16, [cols][K] layout)
__global__ void prep_weights(const float* __restrict__ W1_0, const float* __restrict__ W1rest,
                             const float* __restrict__ W2, unsigned short* __restrict__ wt) {
    int id = blockIdx.x * blockDim.x + threadIdx.x;
    if (id < 32768) {                       // W1_0 [128][256] -> [256][128]
        int k = id >> 8, c = id & 255;
        wt[c * 128 + k] = f2bf(W1_0[id]);
    } else if (id < 163840) {               // W1rest 2x [256][256]
        int t = id - 32768;
        int m = t >> 16, r = t & 65535;
        int k = r >> 8, c = r & 255;
        wt[32768 + m * 65536 + c * 256 + k] = f2bf(W1rest[t]);
    } else if (id < 360448) {               // W2 3x [256][256]
        int t = id - 163840;
        int m = t >> 16, r = t & 65535;
        int k = r >> 8, c = r & 255;
        wt[163840 + m * 65536 + c * 256 + k] = f2bf(W2[t]);
    }
}

// ---------------- pull aggregation (R3 pattern) + optional fused BN+ReLU ----
// out[v] = (1+eps)*T(h[v]) + sum_{u in N(v)} T(h[u])
// T = identity, or relu(bn(.)) with per-column params (lane owns 2*NW fixed cols).
// One 64-lane wave per node, full 512B row gathers, 4-edge unroll for MLP.
template<int H, bool FUSE_BN>
__global__ __launch_bounds__(256) void aggregate_f(
    const unsigned short* __restrict__ h,
    const int* __restrict__ rowptr, const int* __restrict__ idx,
    const float* __restrict__ eps_p, int layer,
    const float* __restrict__ stats, const float* __restrict__ g,
    const float* __restrict__ bt, float invN,
    unsigned short* __restrict__ out, int N) {
    constexpr int NW = H / 128;  // uints (bf16 pairs) per lane
    int lane = threadIdx.x & 63;
    int v = blockIdx.x * 4 + (threadIdx.x >> 6);
    if (v >= N) return;

    float sc[2 * NW], sh[2 * NW];
    if constexpr (FUSE_BN) {
#pragma unroll
        for (int j = 0; j < 2 * NW; ++j) {
            int c = lane * 2 * NW + j;
            float m = stats[c] * invN;
            float var = stats[256 + c] * invN - m * m;
            sc[j] = g[c] * rsqrtf(var + 1e-5f);
            sh[j] = bt[c] - m * sc[j];
        }
    }
    const float s = 1.f + eps_p[layer];
    const unsigned int* hu = (const unsigned int*)h;

    float acc[2 * NW];
    {
        const unsigned int* hv = hu + (size_t)v * (H / 2) + lane * NW;
#pragma unroll
        for (int j = 0; j < NW; ++j) {
            unsigned int r = hv[j];
            float f0 = bf2f(r & 0xffffu), f1 = bf2f(r >> 16);
            if constexpr (FUSE_BN) {
                f0 = fmaxf(f0 * sc[2 * j] + sh[2 * j], 0.f);
                f1 = fmaxf(f1 * sc[2 * j + 1] + sh[2 * j + 1], 0.f);
            }
            acc[2 * j] = s * f0;
            acc[2 * j + 1] = s * f1;
        }
    }
    int e = rowptr[v], end = rowptr[v + 1];
    for (; e + 3 < end; e += 4) {
        int u0 = idx[e], u1 = idx[e + 1], u2 = idx[e + 2], u3 = idx[e + 3];
        const unsigned int* q0 = hu + (size_t)u0 * (H / 2) + lane * NW;
        const unsigned int* q1 = hu + (size_t)u1 * (H / 2) + lane * NW;
        const unsigned int* q2 = hu + (size_t)u2 * (H / 2) + lane * NW;
        const unsigned int* q3 = hu + (size_t)u3 * (H / 2) + lane * NW;
        unsigned int r0[NW], r1[NW], r2[NW], r3[NW];
#pragma unroll
        for (int j = 0; j < NW; ++j) { r0[j] = q0[j]; r1[j] = q1[j]; r2[j] = q2[j]; r3[j] = q3[j]; }
#pragma unroll
        for (int j = 0; j < NW; ++j) {
            float a0 = bf2f(r0[j] & 0xffffu), b0 = bf2f(r0[j] >> 16);
            float a1 = bf2f(r1[j] & 0xffffu), b1 = bf2f(r1[j] >> 16);
            float a2 = bf2f(r2[j] & 0xffffu), b2 = bf2f(r2[j] >> 16);
            float a3 = bf2f(r3[j] & 0xffffu), b3 = bf2f(r3[j] >> 16);
            if constexpr (FUSE_BN) {
                float c0 = sc[2 * j], d0 = sh[2 * j], c1 = sc[2 * j + 1], d1 = sh[2 * j + 1];
                a0 = fmaxf(a0 * c0 + d0, 0.f); b0 = fmaxf(b0 * c1 + d1, 0.f);
                a1 = fmaxf(a1 * c0 + d0, 0.f); b1 = fmaxf(b1 * c1 + d1, 0.f);
                a2 = fmaxf(a2 * c0 + d0, 0.f); b2 = fmaxf(b2 * c1 + d1, 0.f);
                a3 = fmaxf(a3 * c0 + d0, 0.f); b3 = fmaxf(b3 * c1 + d1, 0.f);
            }
            acc[2 * j]     += (a0 + a1) + (a2 + a3);
            acc[2 * j + 1] += (b0 + b1) + (b2 + b3);
        }
    }
    for (; e < end; ++e) {
        int u = idx[e];
        const unsigned int* q = hu + (size_t)u * (H / 2) + lane * NW;
#pragma unroll
        for (int j = 0; j < NW; ++j) {
            unsigned int r = q[j];
            float f0 = bf2f(r & 0xffffu), f1 = bf2f(r >> 16);
            if constexpr (FUSE_BN) {
                f0 = fmaxf(f0 * sc[2 * j] + sh[2 * j], 0.f);
                f1 = fmaxf(f1 * sc[2 * j + 1] + sh[2 * j + 1], 0.f);
            }
            acc[2 * j] += f0;
            acc[2 * j + 1] += f1;
        }
    }
    unsigned int* op = (unsigned int*)out + (size_t)v * (H / 2) + lane * NW;
#pragma unroll
    for (int j = 0; j < NW; ++j)
        op[j] = (unsigned int)f2bf(acc[2 * j]) | ((unsigned int)f2bf(acc[2 * j + 1]) << 16);
}

// ---------------- bf16 MFMA GEMM + bias + BN column stats (R3-proven) ------
template<int K>
__global__ __launch_bounds__(256) void gemm_mfma(const unsigned short* __restrict__ A,
                                                 const unsigned short* __restrict__ Wt,
                                                 const float* __restrict__ bias,
                                                 unsigned short* __restrict__ Y,
                                                 float* __restrict__ stats,
                                                 int Nrows) {
    __shared__ unsigned short sA[2][128 * 32];
    __shared__ unsigned short sB[2][128 * 32];
    const int tid = threadIdx.x;
    const int lane = tid & 63;
    const int wid = tid >> 6;
    const int wm = wid >> 1, wn = wid & 1;
    const int r0 = blockIdx.x * 128;
    const int c0 = blockIdx.y * 128;
    const int chunk0 = wid * 2;

    f32x4 acc[4][4] = {};  // [i(m)][n]

    auto stage = [&](int buf, int k0) {
#pragma unroll
        for (int q = 0; q < 2; ++q) {
            int chunk = chunk0 + q;
            int byteoff = chunk * 1024 + lane * 16;
            int row = byteoff >> 6;          // 64B per LDS row (32 bf16)
            int kk = (byteoff & 63) >> 1;    // bf16 index within row
            const unsigned short* gA = A + (size_t)(r0 + row) * K + k0 + kk;
            const unsigned short* gB = Wt + (size_t)(c0 + row) * K + k0 + kk;
            __builtin_amdgcn_global_load_lds(
                (const __attribute__((address_space(1))) void*)(uintptr_t)gA,
                (__attribute__((address_space(3))) void*)(uintptr_t)(&sA[buf][chunk * 512]),
                16, 0, 0);
            __builtin_amdgcn_global_load_lds(
                (const __attribute__((address_space(1))) void*)(uintptr_t)gB,
                (__attribute__((address_space(3))) void*)(uintptr_t)(&sB[buf][chunk * 512]),
                16, 0, 0);
        }
    };

    const int nt = K / 32;
    stage(0, 0);
    const int krow = lane >> 4;
    const int rl = lane & 15;

    for (int t = 0; t < nt; ++t) {
        __syncthreads();                       // stage(t) complete (barrier drains vmcnt)
        if (t + 1 < nt) stage((t + 1) & 1, (t + 1) * 32);   // prefetch next tile
        const unsigned short* sAb = sA[t & 1];
        const unsigned short* sBb = sB[t & 1];
        short8 a[4], b[4];
#pragma unroll
        for (int i = 0; i < 4; ++i) {
            a[i] = *(const short8*)(sAb + (wm * 64 + i * 16 + rl) * 32 + krow * 8);
            b[i] = *(const short8*)(sBb + (wn * 64 + i * 16 + rl) * 32 + krow * 8);
        }
#pragma unroll
        for (int i = 0; i < 4; ++i)
#pragma unroll
            for (int n = 0; n < 4; ++n)
                asm volatile("v_mfma_f32_16x16x32_bf16 %0, %1, %2, %0"
                             : "+v"(acc[i][n])
                             : "v"(a[i]), "v"(b[n]));
    }
    asm volatile("s_nop 7\n\ts_nop 7" ::);

    const int rg = lane >> 4;
#pragma unroll
    for (int n = 0; n < 4; ++n) {
        int col = c0 + wn * 64 + n * 16 + rl;
        float bv = bias[col];
        float s = 0.f, q2 = 0.f;
#pragma unroll
        for (int i = 0; i < 4; ++i) {
#pragma unroll
            for (int r = 0; r < 4; ++r) {
                int grow = r0 + wm * 64 + i * 16 + rg * 4 + r;
                if (grow < Nrows) {
                    float v = acc[i][n][r] + bv;
                    Y[(size_t)grow * 256 + col] = f2bf(v);
                    s += v;
                    q2 += v * v;
                }
            }
        }
        s  += __shfl_xor(s, 16, 64);  s  += __shfl_xor(s, 32, 64);
        q2 += __shfl_xor(q2, 16, 64); q2 += __shfl_xor(q2, 32, 64);
        if (rg == 0) {
            atomicAdd(&stats[col], s);
            atomicAdd(&stats[256 + col], q2);
        }
    }
}

// ---------------- fused BN params + apply (+optional ReLU) ----------------
__global__ void bn_fuse(const unsigned short* __restrict__ Y, const float* __restrict__ stats,
                        const float* __restrict__ g, const float* __restrict__ bt,
                        float invN, unsigned short* __restrict__ outb, float* __restrict__ outf,
                        int total8, int relu) {
    int i = blockIdx.x * blockDim.x + threadIdx.x;
    if (i >= total8) return;
    int col0 = (i & 31) << 3;
    uint4 y = ((const uint4*)Y)[i];
    unsigned int yy[4] = {y.x, y.y, y.z, y.w};
    float o[8];
#pragma unroll
    for (int j = 0; j < 4; ++j) {
        o[2 * j]     = bf2f(yy[j] & 0xffffu);
        o[2 * j + 1] = bf2f(yy[j] >> 16);
    }
#pragma unroll
    for (int j = 0; j < 8; ++j) {
        int c = col0 + j;
        float mean = stats[c] * invN;
        float var = stats[256 + c] * invN - mean * mean;
        float sc = g[c] * rsqrtf(var + 1e-5f);
        float sh = bt[c] - mean * sc;
        float v = o[j] * sc + sh;
        if (relu) v = fmaxf(v, 0.f);
        o[j] = v;
    }
    if (outf) {
        float4* of = (float4*)outf;
        of[2 * i]     = make_float4(o[0], o[1], o[2], o[3]);
        of[2 * i + 1] = make_float4(o[4], o[5], o[6], o[7]);
    } else {
        uint4 w;
        w.x = (unsigned int)f2bf(o[0]) | ((unsigned int)f2bf(o[1]) << 16);
        w.y = (unsigned int)f2bf(o[2]) | ((unsigned int)f2bf(o[3]) << 16);
        w.z = (unsigned int)f2bf(o[4]) | ((unsigned int)f2bf(o[5]) << 16);
        w.w = (unsigned int)f2bf(o[6]) | ((unsigned int)f2bf(o[7]) << 16);
        ((uint4*)outb)[i] = w;
    }
}

extern "C" void kernel_launch(void* const* d_in, const int* in_sizes, int n_in,
                              void* d_out, int out_size, void* d_ws, size_t ws_size,
                              hipStream_t stream) {
    const float* x      = (const float*)d_in[0];
    const int*   ei     = (const int*)d_in[1];
    const float* eps    = (const float*)d_in[2];
    const float* W1_0   = (const float*)d_in[3];
    const float* W1rest = (const float*)d_in[4];
    const float* b1     = (const float*)d_in[5];
    const float* g1     = (const float*)d_in[6];
    const float* bt1    = (const float*)d_in[7];
    const float* W2     = (const float*)d_in[8];
    const float* b2     = (const float*)d_in[9];
    const float* g2     = (const float*)d_in[10];
    const float* bt2    = (const float*)d_in[11];

    const int N = in_sizes[0] / 128;
    const int E = in_sizes[1] / 2;
    const int* row = ei;
    const int* col = ei + E;
    const int Npad = ((N + 127) / 128) * 128;
    const int nbRow = Npad / 128;

    char* w = (char*)d_ws;
    auto alloc = [&](size_t bytes) {
        char* p = w;
        w += (bytes + 255) & ~(size_t)255;
        return p;
    };
    unsigned short* xb = (unsigned short*)alloc((size_t)Npad * 128 * 2);
    unsigned short* p0 = (unsigned short*)alloc((size_t)Npad * 256 * 2);
    unsigned short* Yb = (unsigned short*)alloc((size_t)Npad * 256 * 2);
    unsigned short* wt = (unsigned short*)alloc((size_t)360448 * 2);
    float* stats = (float*)alloc(3072 * 4);
    int* deg    = (int*)alloc((size_t)N * 4);
    int* cursor = (int*)alloc((size_t)N * 4);
    int* rowptr = (int*)alloc((size_t)(N + 1) * 4);
    int* bs     = (int*)alloc(256 * 4);
    int* bo     = (int*)alloc(256 * 4);
    int* idxb   = (int*)alloc((size_t)E * 4);

    const float invN = 1.f / (float)N;
    const int B = (N + 255) / 256;

    // CSR build
    zero_i<<<(N + 255) / 256, 256, 0, stream>>>(deg, N);
    hist_k<<<(E + 255) / 256, 256, 0, stream>>>(row, deg, E);
    block_sums<<<B, 256, 0, stream>>>(deg, bs, N);
    scan_bs<<<1, 256, 0, stream>>>(bs, bo, B);
    finalize_rowptr<<<B, 256, 0, stream>>>(deg, bo, rowptr, cursor, N, E);
    fill_csr<<<(E + 255) / 256, 256, 0, stream>>>(row, col, cursor, idxb, E);

    // zero: p0/xb tails, stats (every call, in-stream for graph replay)
    int tail16 = (Npad - N) * 256 * 2 / 16;
    int tail16x = (Npad - N) * 128 * 2 / 16;
    {
        uint4* t0 = (uint4*)(p0 + (size_t)N * 256);
        uint4* tx = (uint4*)(xb + (size_t)N * 128);
        int mx = tail16 > 768 ? tail16 : 768;
        zero3<<<(mx + 255) / 256, 256, 0, stream>>>(t0, tail16, tx, tail16x, (uint4*)stats, 768);
    }

    conv_x<<<(N * 32 + 255) / 256, 256, 0, stream>>>(x, xb, N * 32);
    prep_weights<<<(360448 + 255) / 256, 256, 0, stream>>>(W1_0, W1rest, W2, wt);

    const int aggGrid = (N + 3) / 4;
    const int bnGrid = (N * 32 + 255) / 256;
    dim3 gg(nbRow, 2);

    for (int layer = 0; layer < 3; ++layer) {
        float* st = stats + layer * 1024;

        // aggregation -> p0 (layers 1,2: fused BN2(prev)+ReLU applied to pre-BN Yb)
        if (layer == 0)
            aggregate_f<128, false><<<aggGrid, 256, 0, stream>>>(
                xb, rowptr, idxb, eps, 0, nullptr, nullptr, nullptr, invN, p0, N);
        else
            aggregate_f<256, true><<<aggGrid, 256, 0, stream>>>(
                Yb, rowptr, idxb, eps, layer, stats + (layer - 1) * 1024 + 512,
                g2 + (layer - 1) * 256, bt2 + (layer - 1) * 256, invN, p0, N);

        // Linear1 + stats
        if (layer == 0)
            gemm_mfma<128><<<gg, 256, 0, stream>>>(p0, wt, b1, Yb, st, N);
        else
            gemm_mfma<256><<<gg, 256, 0, stream>>>(p0, wt + 32768 + (size_t)(layer - 1) * 65536,
                                                   b1 + layer * 256, Yb, st, N);
        // BN1 + ReLU -> p0 (bf16)
        bn_fuse<<<bnGrid, 256, 0, stream>>>(Yb, st, g1 + layer * 256, bt1 + layer * 256,
                                            invN, p0, nullptr, N * 32, 1);
        // Linear2 + stats
        gemm_mfma<256><<<gg, 256, 0, stream>>>(p0, wt + 163840 + (size_t)layer * 65536,
                                               b2 + layer * 256, Yb, st + 512, N);
        // layers 0,1: BN2+ReLU fused into next layer's aggregation.
        // final layer: BN2 -> fp32 d_out
        if (layer == 2)
            bn_fuse<<<bnGrid, 256, 0, stream>>>(Yb, st + 512, g2 + layer * 256, bt2 + layer * 256,
                                                invN, nullptr, (float*)d_out, N * 32, 0);
    }
}

// Round 6
// 515.583 us; speedup vs baseline: 2.6030x; 1.0754x over previous
//
#include <hip/hip_runtime.h>
#include <hip/hip_bf16.h>
#include <math.h>
#include <stdint.h>

typedef short short8 __attribute__((ext_vector_type(8)));
typedef float f32x4 __attribute__((ext_vector_type(4)));

__device__ __forceinline__ float bf2f(unsigned int u) {
    union { unsigned int i; float f; } x; x.i = u << 16; return x.f;
}
__device__ __forceinline__ unsigned short f2bf(float f) {
    union { float f; unsigned int i; } x; x.f = f;
    unsigned int r = x.i + 0x7fffu + ((x.i >> 16) & 1u);
    return (unsigned short)(r >> 16);
}

// ---------------- CSR build ----------------
__global__ void zero_i(int* __restrict__ p, int n) {
    int i = blockIdx.x * blockDim.x + threadIdx.x;
    if (i < n) p[i] = 0;
}
__global__ void hist_k(const int* __restrict__ row, int* __restrict__ deg, int E) {
    int e = blockIdx.x * blockDim.x + threadIdx.x;
    if (e < E) atomicAdd(&deg[row[e]], 1);
}
__global__ void block_sums(const int* __restrict__ deg, int* __restrict__ bs, int N) {
    __shared__ int tmp[256];
    int t = threadIdx.x;
    int i = blockIdx.x * 256 + t;
    tmp[t] = (i < N) ? deg[i] : 0;
    __syncthreads();
    for (int off = 128; off > 0; off >>= 1) {
        if (t < off) tmp[t] += tmp[t + off];
        __syncthreads();
    }
    if (t == 0) bs[blockIdx.x] = tmp[0];
}
__global__ void scan_bs(const int* __restrict__ bs, int* __restrict__ bo, int B) {
    __shared__ int tmp[256];
    int t = threadIdx.x;
    int v = (t < B) ? bs[t] : 0;
    tmp[t] = v;
    __syncthreads();
    for (int off = 1; off < 256; off <<= 1) {
        int x = (t >= off) ? tmp[t - off] : 0;
        __syncthreads();
        tmp[t] += x;
        __syncthreads();
    }
    bo[t] = tmp[t] - v;
}
__global__ void finalize_rowptr(const int* __restrict__ deg, const int* __restrict__ bo,
                                int* __restrict__ rowptr, int* __restrict__ cursor,
                                int N, int E) {
    __shared__ int tmp[256];
    int t = threadIdx.x;
    int i = blockIdx.x * 256 + t;
    int v = (i < N) ? deg[i] : 0;
    tmp[t] = v;
    __syncthreads();
    for (int off = 1; off < 256; off <<= 1) {
        int x = (t >= off) ? tmp[t - off] : 0;
        __syncthreads();
        tmp[t] += x;
        __syncthreads();
    }
    int excl = tmp[t] - v + bo[blockIdx.x];
    if (i < N) { rowptr[i] = excl; cursor[i] = excl; }
    if (i == N) rowptr[N] = E;
}
__global__ void fill_csr(const int* __restrict__ row, const int* __restrict__ col,
                         int* __restrict__ cursor, int* __restrict__ idx, int E) {
    int e = blockIdx.x * blockDim.x + threadIdx.x;
    if (e < E) {
        int p = atomicAdd(&cursor[row[e]], 1);
        idx[p] = col[e];
    }
}

// ---------------- misc prep ----------------
__global__ void zero3(uint4* a, int na, uint4* b, int nb, uint4* c, int nc) {
    int i = blockIdx.x * blockDim.x + threadIdx.x;
    uint4 z = make_uint4(0, 0, 0, 0);
    if (i < na) a[i] = z;
    if (i < nb) b[i] = z;
    if (i < nc) c[i] = z;
}

__global__ void conv_x(const float* __restrict__ x, unsigned short* __restrict__ xb, int total4) {
    int i = blockIdx.x * blockDim.x + threadIdx.x;
    if (i >= total4) return;
    float4 v = *(const float4*)(x + (size_t)i * 4);
    unsigned int lo = (unsigned int)f2bf(v.x) | ((unsigned int)f2bf(v.y) << 16);
    unsigned int hi = (unsigned int)f2bf(v.z) | ((unsigned int)f2bf(v.w) << 16);
    *(uint2*)(xb + (size_t)i * 4) = make_uint2(lo, hi);
}

// transpose+convert all 6 weight matrices into wt (bf16, [cols][K] layout)
__global__ void prep_weights(const float* __restrict__ W1_0, const float* __restrict__ W1rest,
                             const float* __restrict__ W2, unsigned short* __restrict__ wt) {
    int id = blockIdx.x * blockDim.x + threadIdx.x;
    if (id < 32768) {                       // W1_0 [128][256] -> [256][128]
        int k = id >> 8, c = id & 255;
        wt[c * 128 + k] = f2bf(W1_0[id]);
    } else if (id < 163840) {               // W1rest 2x [256][256]
        int t = id - 32768;
        int m = t >> 16, r = t & 65535;
        int k = r >> 8, c = r & 255;
        wt[32768 + m * 65536 + c * 256 + k] = f2bf(W1rest[t]);
    } else if (id < 360448) {               // W2 3x [256][256]
        int t = id - 163840;
        int m = t >> 16, r = t & 65535;
        int k = r >> 8, c = r & 255;
        wt[163840 + m * 65536 + c * 256 + k] = f2bf(W2[t]);
    }
}

// BN params: par[c] = g*rsqrt(var+eps), par[256+c] = bt - mean*par[c]
__global__ void bnpar(const float* __restrict__ stats, const float* __restrict__ g,
                      const float* __restrict__ bt, float* __restrict__ par, float invN) {
    int c = threadIdx.x;
    float m = stats[c] * invN;
    float v = stats[256 + c] * invN - m * m;
    float s = g[c] * rsqrtf(v + 1e-5f);
    par[c] = s;
    par[256 + c] = bt[c] - m * s;
}

// ---------------- pull aggregation + optional fused BN+ReLU on source ------
// out[v] = (1+eps)*T(h[v]) + sum_{u in N(v)} T(h[u]),  T = id or relu(x*sc+sh).
// One 64-lane wave per node, full-row gathers, 8/4/1-edge unroll for MLP.
template<int H, bool FUSE_BN>
__global__ __launch_bounds__(256) void aggregate_f(
    const unsigned short* __restrict__ h,
    const int* __restrict__ rowptr, const int* __restrict__ idx,
    const float* __restrict__ eps_p, int layer,
    const float* __restrict__ par,
    unsigned short* __restrict__ out, int N) {
    constexpr int NW = H / 128;  // uints (bf16 pairs) per lane
    int lane = threadIdx.x & 63;
    int v = blockIdx.x * 4 + (threadIdx.x >> 6);
    if (v >= N) return;

    float sc[2 * NW], sh[2 * NW];
    if constexpr (FUSE_BN) {
#pragma unroll
        for (int j = 0; j < 2 * NW; ++j) {
            int c = lane * 2 * NW + j;
            sc[j] = par[c];
            sh[j] = par[256 + c];
        }
    }
    const float s = 1.f + eps_p[layer];
    const unsigned int* hu = (const unsigned int*)h;

    float acc[2 * NW];
    {
        const unsigned int* hv = hu + (size_t)v * (H / 2) + lane * NW;
#pragma unroll
        for (int j = 0; j < NW; ++j) {
            unsigned int r = hv[j];
            float f0 = bf2f(r & 0xffffu), f1 = bf2f(r >> 16);
            if constexpr (FUSE_BN) {
                f0 = fmaxf(f0 * sc[2 * j] + sh[2 * j], 0.f);
                f1 = fmaxf(f1 * sc[2 * j + 1] + sh[2 * j + 1], 0.f);
            }
            acc[2 * j] = s * f0;
            acc[2 * j + 1] = s * f1;
        }
    }
    int e = rowptr[v], end = rowptr[v + 1];
    // 8-edge unroll: more loads in flight (latency-bound gather)
    for (; e + 7 < end; e += 8) {
        unsigned int r[8][NW];
#pragma unroll
        for (int k = 0; k < 8; ++k) {
            const unsigned int* q = hu + (size_t)idx[e + k] * (H / 2) + lane * NW;
#pragma unroll
            for (int j = 0; j < NW; ++j) r[k][j] = q[j];
        }
#pragma unroll
        for (int j = 0; j < NW; ++j) {
            float t0 = 0.f, t1 = 0.f;
#pragma unroll
            for (int k = 0; k < 8; ++k) {
                float f0 = bf2f(r[k][j] & 0xffffu), f1 = bf2f(r[k][j] >> 16);
                if constexpr (FUSE_BN) {
                    f0 = fmaxf(f0 * sc[2 * j] + sh[2 * j], 0.f);
                    f1 = fmaxf(f1 * sc[2 * j + 1] + sh[2 * j + 1], 0.f);
                }
                t0 += f0; t1 += f1;
            }
            acc[2 * j] += t0;
            acc[2 * j + 1] += t1;
        }
    }
    for (; e + 3 < end; e += 4) {
        unsigned int r[4][NW];
#pragma unroll
        for (int k = 0; k < 4; ++k) {
            const unsigned int* q = hu + (size_t)idx[e + k] * (H / 2) + lane * NW;
#pragma unroll
            for (int j = 0; j < NW; ++j) r[k][j] = q[j];
        }
#pragma unroll
        for (int j = 0; j < NW; ++j) {
            float t0 = 0.f, t1 = 0.f;
#pragma unroll
            for (int k = 0; k < 4; ++k) {
                float f0 = bf2f(r[k][j] & 0xffffu), f1 = bf2f(r[k][j] >> 16);
                if constexpr (FUSE_BN) {
                    f0 = fmaxf(f0 * sc[2 * j] + sh[2 * j], 0.f);
                    f1 = fmaxf(f1 * sc[2 * j + 1] + sh[2 * j + 1], 0.f);
                }
                t0 += f0; t1 += f1;
            }
            acc[2 * j] += t0;
            acc[2 * j + 1] += t1;
        }
    }
    for (; e < end; ++e) {
        const unsigned int* q = hu + (size_t)idx[e] * (H / 2) + lane * NW;
#pragma unroll
        for (int j = 0; j < NW; ++j) {
            unsigned int r = q[j];
            float f0 = bf2f(r & 0xffffu), f1 = bf2f(r >> 16);
            if constexpr (FUSE_BN) {
                f0 = fmaxf(f0 * sc[2 * j] + sh[2 * j], 0.f);
                f1 = fmaxf(f1 * sc[2 * j + 1] + sh[2 * j + 1], 0.f);
            }
            acc[2 * j] += f0;
            acc[2 * j + 1] += f1;
        }
    }
    unsigned int* op = (unsigned int*)out + (size_t)v * (H / 2) + lane * NW;
#pragma unroll
    for (int j = 0; j < NW; ++j)
        op[j] = (unsigned int)f2bf(acc[2 * j]) | ((unsigned int)f2bf(acc[2 * j + 1]) << 16);
}

// ---------------- bf16 MFMA GEMM + bias + BN column stats ----------------
// TRANS_A: A-tile reg-staged with fused BN1+ReLU (par) before LDS write;
// B always global_load_lds direct. Stats: wm-pair LDS combine -> 1 atomic/col/block.
template<int K, bool TRANS_A>
__global__ __launch_bounds__(256) void gemm_mfma(const unsigned short* __restrict__ A,
                                                 const unsigned short* __restrict__ Wt,
                                                 const float* __restrict__ bias,
                                                 const float* __restrict__ par,
                                                 unsigned short* __restrict__ Y,
                                                 float* __restrict__ stats,
                                                 int Nrows) {
    __shared__ unsigned short sA[2][128 * 32];
    __shared__ unsigned short sB[2][128 * 32];
    __shared__ float reds[128], redq[128];
    const int tid = threadIdx.x;
    const int lane = tid & 63;
    const int wid = tid >> 6;
    const int wm = wid >> 1, wn = wid & 1;
    const int r0 = blockIdx.x * 128;
    const int c0 = blockIdx.y * 128;
    const int chunk0 = wid * 2;
    const int akk = (lane & 3) * 8;        // bf16 col offset within 32-wide K-tile
    const int arow_l = lane >> 2;          // row within 16-row chunk

    f32x4 acc[4][4] = {};

    auto stageB = [&](int buf, int k0) {
#pragma unroll
        for (int q = 0; q < 2; ++q) {
            int chunk = chunk0 + q;
            int byteoff = chunk * 1024 + lane * 16;
            int row = byteoff >> 6;
            int kk = (byteoff & 63) >> 1;
            const unsigned short* gB = Wt + (size_t)(c0 + row) * K + k0 + kk;
            __builtin_amdgcn_global_load_lds(
                (const __attribute__((address_space(1))) void*)(uintptr_t)gB,
                (__attribute__((address_space(3))) void*)(uintptr_t)(&sB[buf][chunk * 512]),
                16, 0, 0);
        }
    };
    auto stageA_direct = [&](int buf, int k0) {
#pragma unroll
        for (int q = 0; q < 2; ++q) {
            int chunk = chunk0 + q;
            int byteoff = chunk * 1024 + lane * 16;
            int row = byteoff >> 6;
            int kk = (byteoff & 63) >> 1;
            const unsigned short* gA = A + (size_t)(r0 + row) * K + k0 + kk;
            __builtin_amdgcn_global_load_lds(
                (const __attribute__((address_space(1))) void*)(uintptr_t)gA,
                (__attribute__((address_space(3))) void*)(uintptr_t)(&sA[buf][chunk * 512]),
                16, 0, 0);
        }
    };
    uint4 areg[2];
    auto loadA = [&](int k0) {
#pragma unroll
        for (int q = 0; q < 2; ++q) {
            int row = (chunk0 + q) * 16 + arow_l;
            areg[q] = *(const uint4*)(A + (size_t)(r0 + row) * K + k0 + akk);
        }
    };
    auto writeA = [&](int buf, int k0) {
        float4 sca = *(const float4*)&par[k0 + akk];
        float4 scb = *(const float4*)&par[k0 + akk + 4];
        float4 sha = *(const float4*)&par[256 + k0 + akk];
        float4 shb = *(const float4*)&par[256 + k0 + akk + 4];
#pragma unroll
        for (int q = 0; q < 2; ++q) {
            uint4 u = areg[q];
            float f0 = fmaxf(bf2f(u.x & 0xffffu) * sca.x + sha.x, 0.f);
            float f1 = fmaxf(bf2f(u.x >> 16)     * sca.y + sha.y, 0.f);
            float f2 = fmaxf(bf2f(u.y & 0xffffu) * sca.z + sha.z, 0.f);
            float f3 = fmaxf(bf2f(u.y >> 16)     * sca.w + sha.w, 0.f);
            float f4 = fmaxf(bf2f(u.z & 0xffffu) * scb.x + shb.x, 0.f);
            float f5 = fmaxf(bf2f(u.z >> 16)     * scb.y + shb.y, 0.f);
            float f6 = fmaxf(bf2f(u.w & 0xffffu) * scb.z + shb.z, 0.f);
            float f7 = fmaxf(bf2f(u.w >> 16)     * scb.w + shb.w, 0.f);
            uint4 w;
            w.x = (unsigned int)f2bf(f0) | ((unsigned int)f2bf(f1) << 16);
            w.y = (unsigned int)f2bf(f2) | ((unsigned int)f2bf(f3) << 16);
            w.z = (unsigned int)f2bf(f4) | ((unsigned int)f2bf(f5) << 16);
            w.w = (unsigned int)f2bf(f6) | ((unsigned int)f2bf(f7) << 16);
            *(uint4*)&sA[buf][(chunk0 + q) * 512 + lane * 8] = w;
        }
    };

    const int nt = K / 32;
    if constexpr (TRANS_A) { loadA(0); } else { stageA_direct(0, 0); }
    stageB(0, 0);
    const int krow = lane >> 4;
    const int rl = lane & 15;

    for (int t = 0; t < nt; ++t) {
        if constexpr (TRANS_A) writeA(t & 1, t * 32);
        __syncthreads();   // tile t fully in LDS (vm + lgkm drained per wave)
        if (t + 1 < nt) {
            stageB((t + 1) & 1, (t + 1) * 32);
            if constexpr (TRANS_A) loadA((t + 1) * 32);
            else stageA_direct((t + 1) & 1, (t + 1) * 32);
        }
        const unsigned short* sAb = sA[t & 1];
        const unsigned short* sBb = sB[t & 1];
        short8 a[4], b[4];
#pragma unroll
        for (int i = 0; i < 4; ++i) {
            a[i] = *(const short8*)(sAb + (wm * 64 + i * 16 + rl) * 32 + krow * 8);
            b[i] = *(const short8*)(sBb + (wn * 64 + i * 16 + rl) * 32 + krow * 8);
        }
#pragma unroll
        for (int i = 0; i < 4; ++i)
#pragma unroll
            for (int n = 0; n < 4; ++n)
                asm volatile("v_mfma_f32_16x16x32_bf16 %0, %1, %2, %0"
                             : "+v"(acc[i][n])
                             : "v"(a[i]), "v"(b[n]));
    }
    asm volatile("s_nop 7\n\ts_nop 7" ::);

    const int rg = lane >> 4;
    float ssum[4], qsum[4];
#pragma unroll
    for (int n = 0; n < 4; ++n) {
        int col = c0 + wn * 64 + n * 16 + rl;
        float bv = bias[col];
        float s = 0.f, q2 = 0.f;
#pragma unroll
        for (int i = 0; i < 4; ++i) {
#pragma unroll
            for (int r = 0; r < 4; ++r) {
                int grow = r0 + wm * 64 + i * 16 + rg * 4 + r;
                if (grow < Nrows) {
                    float v = acc[i][n][r] + bv;
                    Y[(size_t)grow * 256 + col] = f2bf(v);
                    s += v;
                    q2 += v * v;
                }
            }
        }
        s  += __shfl_xor(s, 16, 64);  s  += __shfl_xor(s, 32, 64);
        q2 += __shfl_xor(q2, 16, 64); q2 += __shfl_xor(q2, 32, 64);
        ssum[n] = s; qsum[n] = q2;
    }
    // combine the two wm-waves via LDS, then one atomic per column per block
    if (wm == 0 && rg == 0) {
#pragma unroll
        for (int n = 0; n < 4; ++n) {
            int lc = wn * 64 + n * 16 + rl;
            reds[lc] = ssum[n];
            redq[lc] = qsum[n];
        }
    }
    __syncthreads();
    if (wm == 1 && rg == 0) {
#pragma unroll
        for (int n = 0; n < 4; ++n) {
            int lc = wn * 64 + n * 16 + rl;
            int c = c0 + lc;
            atomicAdd(&stats[c], ssum[n] + reds[lc]);
            atomicAdd(&stats[256 + c], qsum[n] + redq[lc]);
        }
    }
}

// ---------------- final BN apply -> fp32 out ----------------
__global__ void bn_fuse(const unsigned short* __restrict__ Y, const float* __restrict__ stats,
                        const float* __restrict__ g, const float* __restrict__ bt,
                        float invN, float* __restrict__ outf, int total8) {
    int i = blockIdx.x * blockDim.x + threadIdx.x;
    if (i >= total8) return;
    int col0 = (i & 31) << 3;
    uint4 y = ((const uint4*)Y)[i];
    unsigned int yy[4] = {y.x, y.y, y.z, y.w};
    float o[8];
#pragma unroll
    for (int j = 0; j < 4; ++j) {
        o[2 * j]     = bf2f(yy[j] & 0xffffu);
        o[2 * j + 1] = bf2f(yy[j] >> 16);
    }
#pragma unroll
    for (int j = 0; j < 8; ++j) {
        int c = col0 + j;
        float mean = stats[c] * invN;
        float var = stats[256 + c] * invN - mean * mean;
        float sc = g[c] * rsqrtf(var + 1e-5f);
        float sh = bt[c] - mean * sc;
        o[j] = o[j] * sc + sh;
    }
    float4* of = (float4*)outf;
    of[2 * i]     = make_float4(o[0], o[1], o[2], o[3]);
    of[2 * i + 1] = make_float4(o[4], o[5], o[6], o[7]);
}

extern "C" void kernel_launch(void* const* d_in, const int* in_sizes, int n_in,
                              void* d_out, int out_size, void* d_ws, size_t ws_size,
                              hipStream_t stream) {
    const float* x      = (const float*)d_in[0];
    const int*   ei     = (const int*)d_in[1];
    const float* eps    = (const float*)d_in[2];
    const float* W1_0   = (const float*)d_in[3];
    const float* W1rest = (const float*)d_in[4];
    const float* b1     = (const float*)d_in[5];
    const float* g1     = (const float*)d_in[6];
    const float* bt1    = (const float*)d_in[7];
    const float* W2     = (const float*)d_in[8];
    const float* b2     = (const float*)d_in[9];
    const float* g2     = (const float*)d_in[10];
    const float* bt2    = (const float*)d_in[11];

    const int N = in_sizes[0] / 128;
    const int E = in_sizes[1] / 2;
    const int* row = ei;
    const int* col = ei + E;
    const int Npad = ((N + 127) / 128) * 128;
    const int nbRow = Npad / 128;

    char* w = (char*)d_ws;
    auto alloc = [&](size_t bytes) {
        char* p = w;
        w += (bytes + 255) & ~(size_t)255;
        return p;
    };
    unsigned short* xb = (unsigned short*)alloc((size_t)Npad * 128 * 2);
    unsigned short* p0 = (unsigned short*)alloc((size_t)Npad * 256 * 2);
    unsigned short* p1 = (unsigned short*)alloc((size_t)Npad * 256 * 2);
    unsigned short* Yb = (unsigned short*)alloc((size_t)Npad * 256 * 2);
    unsigned short* wt = (unsigned short*)alloc((size_t)360448 * 2);
    float* stats  = (float*)alloc(3072 * 4);
    float* params = (float*)alloc(3072 * 4);
    int* deg    = (int*)alloc((size_t)N * 4);
    int* cursor = (int*)alloc((size_t)N * 4);
    int* rowptr = (int*)alloc((size_t)(N + 1) * 4);
    int* bs     = (int*)alloc(256 * 4);
    int* bo     = (int*)alloc(256 * 4);
    int* idxb   = (int*)alloc((size_t)E * 4);

    const float invN = 1.f / (float)N;
    const int B = (N + 255) / 256;

    // CSR build
    zero_i<<<(N + 255) / 256, 256, 0, stream>>>(deg, N);
    hist_k<<<(E + 255) / 256, 256, 0, stream>>>(row, deg, E);
    block_sums<<<B, 256, 0, stream>>>(deg, bs, N);
    scan_bs<<<1, 256, 0, stream>>>(bs, bo, B);
    finalize_rowptr<<<B, 256, 0, stream>>>(deg, bo, rowptr, cursor, N, E);
    fill_csr<<<(E + 255) / 256, 256, 0, stream>>>(row, col, cursor, idxb, E);

    // zero p0/p1 tails + stats (in-stream, every call for graph replay)
    int tail16 = (Npad - N) * 256 * 2 / 16;
    {
        uint4* t0 = (uint4*)(p0 + (size_t)N * 256);
        uint4* t1 = (uint4*)(p1 + (size_t)N * 256);
        int mx = tail16 > 768 ? tail16 : 768;
        zero3<<<(mx + 255) / 256, 256, 0, stream>>>(t0, tail16, t1, tail16, (uint4*)stats, 768);
    }

    conv_x<<<(N * 32 + 255) / 256, 256, 0, stream>>>(x, xb, N * 32);
    prep_weights<<<(360448 + 255) / 256, 256, 0, stream>>>(W1_0, W1rest, W2, wt);

    const int aggGrid = (N + 3) / 4;
    const int bnGrid = (N * 32 + 255) / 256;
    dim3 gg(nbRow, 2);

    for (int layer = 0; layer < 3; ++layer) {
        float* st1 = stats + layer * 1024;
        float* st2 = st1 + 512;
        float* pr1 = params + layer * 1024;
        float* pr2 = pr1 + 512;

        // aggregation -> p1 (layers 1,2: fused BN2(prev)+ReLU on pre-BN input)
        if (layer == 0)
            aggregate_f<128, false><<<aggGrid, 256, 0, stream>>>(
                xb, rowptr, idxb, eps, 0, nullptr, p1, N);
        else
            aggregate_f<256, true><<<aggGrid, 256, 0, stream>>>(
                p0, rowptr, idxb, eps, layer, params + (layer - 1) * 1024 + 512, p1, N);

        // Linear1 + stats -> Yb (pre-BN1)
        if (layer == 0)
            gemm_mfma<128, false><<<gg, 256, 0, stream>>>(p1, wt, b1, nullptr, Yb, st1, N);
        else
            gemm_mfma<256, false><<<gg, 256, 0, stream>>>(
                p1, wt + 32768 + (size_t)(layer - 1) * 65536, b1 + layer * 256, nullptr, Yb, st1, N);

        bnpar<<<1, 256, 0, stream>>>(st1, g1 + layer * 256, bt1 + layer * 256, pr1, invN);

        // Linear2 with fused BN1+ReLU on A -> p0 (pre-BN2) + stats
        gemm_mfma<256, true><<<gg, 256, 0, stream>>>(
            Yb, wt + 163840 + (size_t)layer * 65536, b2 + layer * 256, pr1, p0, st2, N);

        if (layer < 2)
            bnpar<<<1, 256, 0, stream>>>(st2, g2 + layer * 256, bt2 + layer * 256, pr2, invN);
        else
            bn_fuse<<<bnGrid, 256, 0, stream>>>(p0, st2, g2 + layer * 256, bt2 + layer * 256,
                                                invN, (float*)d_out, N * 32);
    }
}